// Round 1
// baseline (70.887 us; speedup 1.0000x reference)
//
#include <hip/hip_runtime.h>
#include <math.h>

// Dims (fixed per reference)
#define B   128
#define L   50
#define V   100000
#define ND  4
#define D   64

// out layout: P_v (B*V) | infomax_loss (1) | gnn (B*ND*L*D)

__device__ __forceinline__ float log_sigmoid(float x) {
    // jax.nn.log_sigmoid(x) = -softplus(-x), numerically stable
    if (x >= 0.f) return -log1pf(expf(-x));
    return x - log1pf(expf(x));
}

// K1: gather session_emb = emb_i[nodes], write gnn (4 broadcast copies),
//     compute masked-mean graph_rep and last-item row.
__global__ __launch_bounds__(256) void k1_gather(
    const int* __restrict__ nodes, const int* __restrict__ mask,
    const int* __restrict__ sli, const float* __restrict__ emb_i,
    float* __restrict__ gnn_out, float* __restrict__ gr,
    float* __restrict__ last)
{
    const int b = blockIdx.x;
    const int t = threadIdx.x;
    __shared__ int   s_nodes[L];
    __shared__ float s_mask[L];
    __shared__ float s_part[4][D];
    if (t < L) {
        s_nodes[t] = nodes[b * L + t];
        s_mask[t]  = (float)mask[b * L + t];
    }
    __syncthreads();
    const int d  = t & 63;
    const int l0 = t >> 6;
    float acc = 0.f;
    for (int l = l0; l < L; l += 4) {
        float val = emb_i[(size_t)s_nodes[l] * D + d];
        size_t o = ((size_t)(b * ND + 0) * L + l) * D + d;
        gnn_out[o]                   = val;
        gnn_out[o + (size_t)L * D]   = val;
        gnn_out[o + 2*(size_t)L * D] = val;
        gnn_out[o + 3*(size_t)L * D] = val;
        acc += s_mask[l] * val;
    }
    s_part[l0][d] = acc;
    __syncthreads();
    if (t < D) {
        float msum = 0.f;
        for (int l = 0; l < L; ++l) msum += s_mask[l];
        float s = s_part[0][t] + s_part[1][t] + s_part[2][t] + s_part[3][t];
        gr[b * D + t] = s / msum;
        int idx = sli[b];
        last[b * D + t] = emb_i[(size_t)s_nodes[idx] * D + t];
    }
}

// K2: per b: u[b] = W_im @ graph_rep[b]; h[b] = tanh([gr|last] @ W_pvsd + b_pvsd)
__global__ __launch_bounds__(64) void k2_proj(
    const float* __restrict__ gr, const float* __restrict__ last,
    const float* __restrict__ W_pvsd, const float* __restrict__ b_pvsd,
    const float* __restrict__ W_im,
    float* __restrict__ u, float* __restrict__ h)
{
    const int b = blockIdx.x;
    const int d = threadIdx.x;
    __shared__ float s_gr[D], s_last[D];
    s_gr[d]   = gr[b * D + d];
    s_last[d] = last[b * D + d];
    __syncthreads();
    float uu = 0.f;
    #pragma unroll
    for (int e = 0; e < D; ++e) uu += W_im[d * D + e] * s_gr[e];
    u[b * D + d] = uu;
    float pre = b_pvsd[d];
    #pragma unroll
    for (int k = 0; k < D; ++k) pre += s_gr[k]   * W_pvsd[k * D + d];
    #pragma unroll
    for (int k = 0; k < D; ++k) pre += s_last[k] * W_pvsd[(D + k) * D + d];
    h[b * D + d] = tanhf(pre);
}

// K3: infomax partial sums per b: sum_l log_sigmoid(se.u_b), log_sigmoid(-se.u_{b-1})
__global__ __launch_bounds__(64) void k3_infomax(
    const float* __restrict__ u, const float* __restrict__ gnn,
    float* __restrict__ pos_part, float* __restrict__ neg_part)
{
    const int b = blockIdx.x;
    const int t = threadIdx.x;
    __shared__ float s_up[D], s_un[D];
    const int bm1 = (b + B - 1) % B;
    s_up[t] = u[b * D + t];
    s_un[t] = u[bm1 * D + t];
    __syncthreads();
    float lsp = 0.f, lsn = 0.f;
    if (t < L) {
        const float* se = gnn + ((size_t)(b * ND) * L + t) * D;  // n=0 copy
        float sp = 0.f, sn = 0.f;
        #pragma unroll
        for (int d2 = 0; d2 < D; ++d2) {
            float vv = se[d2];
            sp += vv * s_up[d2];
            sn += vv * s_un[d2];
        }
        lsp = log_sigmoid(sp);
        lsn = log_sigmoid(-sn);
    }
    for (int off = 32; off > 0; off >>= 1) {
        lsp += __shfl_down(lsp, off);
        lsn += __shfl_down(lsn, off);
    }
    if (t == 0) { pos_part[b] = lsp; neg_part[b] = lsn; }
}

// K4: final scalar loss (ND cancels: loss = -(sum_pos + sum_neg)/(B*L))
__global__ __launch_bounds__(128) void k4_loss(
    const float* __restrict__ pos_part, const float* __restrict__ neg_part,
    float* __restrict__ out_loss)
{
    const int t = threadIdx.x;
    __shared__ float s[128];
    s[t] = pos_part[t] + neg_part[t];
    __syncthreads();
    for (int off = 64; off > 0; off >>= 1) {
        if (t < off) s[t] += s[t + off];
        __syncthreads();
    }
    if (t == 0) out_loss[0] = -s[0] / (float)(B * L);
}

// K5: P_v[b,v] = h[b] . emb_i[v]   (sum_n softmax over ND == 1 exactly-enough)
// lane -> v (coalesced stores), emb row in VGPRs, h via wave-uniform s_loads.
__global__ __launch_bounds__(256) void k5_pv(
    const float* __restrict__ h, const float* __restrict__ emb_i,
    float* __restrict__ pv)
{
    const int v  = blockIdx.x * 256 + threadIdx.x;
    const int b0 = blockIdx.y * (B / 2);
    const bool active = (v < V);
    float row[D];
    if (active) {
        const float4* r4 = reinterpret_cast<const float4*>(emb_i + (size_t)v * D);
        #pragma unroll
        for (int i = 0; i < D / 4; ++i) {
            float4 f = r4[i];
            row[4*i] = f.x; row[4*i+1] = f.y; row[4*i+2] = f.z; row[4*i+3] = f.w;
        }
    } else {
        #pragma unroll
        for (int i = 0; i < D; ++i) row[i] = 0.f;
    }
    for (int b = b0; b < b0 + B / 2; ++b) {
        const float* hb = h + b * D;   // uniform address -> s_load
        float a0 = 0.f, a1 = 0.f, a2 = 0.f, a3 = 0.f;
        #pragma unroll
        for (int d2 = 0; d2 < D; d2 += 4) {
            a0 += row[d2]     * hb[d2];
            a1 += row[d2 + 1] * hb[d2 + 1];
            a2 += row[d2 + 2] * hb[d2 + 2];
            a3 += row[d2 + 3] * hb[d2 + 3];
        }
        if (active) pv[(size_t)b * V + v] = (a0 + a1) + (a2 + a3);
    }
}

extern "C" void kernel_launch(void* const* d_in, const int* in_sizes, int n_in,
                              void* d_out, int out_size, void* d_ws, size_t ws_size,
                              hipStream_t stream)
{
    const int*   nodes  = (const int*)d_in[0];
    const int*   sli    = (const int*)d_in[4];
    const int*   mask   = (const int*)d_in[6];
    const float* emb_i  = (const float*)d_in[7];
    const float* W_pvsd = (const float*)d_in[13];
    const float* b_pvsd = (const float*)d_in[14];
    const float* W_im   = (const float*)d_in[15];

    float* pv   = (float*)d_out;               // B*V
    float* loss = pv + (size_t)B * V;          // 1
    float* gnn  = loss + 1;                    // B*ND*L*D

    float* ws       = (float*)d_ws;
    float* gr       = ws;                      // B*D
    float* last     = gr + B * D;              // B*D
    float* u        = last + B * D;            // B*D
    float* h        = u + B * D;               // B*D
    float* pos_part = h + B * D;               // B
    float* neg_part = pos_part + B;            // B

    k1_gather<<<B, 256, 0, stream>>>(nodes, mask, sli, emb_i, gnn, gr, last);
    k2_proj<<<B, 64, 0, stream>>>(gr, last, W_pvsd, b_pvsd, W_im, u, h);
    k3_infomax<<<B, 64, 0, stream>>>(u, gnn, pos_part, neg_part);
    k4_loss<<<1, 128, 0, stream>>>(pos_part, neg_part, loss);
    k5_pv<<<dim3((V + 255) / 256, 2), 256, 0, stream>>>(h, emb_i, pv);
}